// Round 6
// baseline (515.364 us; speedup 1.0000x reference)
//
#include <hip/hip_runtime.h>

#define N_NODES 50000
#define N_EDGES 800000
#define D 128
#define CAP 48      // bucket capacity per dst node (max in-degree ~45 for this dataset)
#define OVF_CAP 4096

#define NPART 40    // scatter partitions (1 block each, LDS-resident bucket region)
#define PNODES 1250 // nodes per partition = 50000/40

typedef unsigned short bf16_t;
typedef __attribute__((ext_vector_type(8))) short short8v;   // 8 bf16 = 4 VGPR (MFMA A/B frag)
typedef __attribute__((ext_vector_type(4))) float f32x4;     // MFMA C/D frag

__device__ inline float bf2f(bf16_t u) {
    union { unsigned int i; float f; } v;
    v.i = ((unsigned int)u) << 16;
    return v.f;
}
__device__ inline bf16_t f2bf(float f) {
    union { float f; unsigned int i; } v;
    v.f = f;
    unsigned int u = v.i;
    unsigned int r = (u + 0x7FFFu + ((u >> 16) & 1u)) >> 16;  // RNE
    return (bf16_t)r;
}
// bf16 pair packed in a u32 (little-endian: lo half = even col, hi half = odd col)
__device__ inline float u2f_lo(unsigned int u) {
    union { unsigned int i; float f; } x; x.i = u << 16; return x.f;
}
__device__ inline float u2f_hi(unsigned int u) {
    union { unsigned int i; float f; } x; x.i = u & 0xFFFF0000u; return x.f;
}

// =============== single-kernel LDS-resident scatter ===============
// Replaces the hist/scan/place counting-sort trio. Evidence trail:
//  - rounds 0-2: 1.6 M global atomics = ~51 MB memory-side fabric writes,
//    invariant to partitioning -> global atomics are unusable here.
//  - rounds 3-5: counting sort fixed atomics but place_kernel's 800 K
//    scattered 2 B stores re-created ~51 MB of partial-line writeback, and
//    scan_kernel was latency-bound (160 serial loads x 25 K threads).
// Fix: 40 blocks (1 block/CU, 130 KB LDS), each scans ALL edges and builds
// its 1250-node partition's complete bucket + in/out-degree counts in LDS,
// then writes everything out dense+coalesced. Zero global atomics, zero
// scattered global stores, zero cross-block offset machinery.
__global__ __launch_bounds__(1024) void scatter_kernel(
    const int* __restrict__ src, const int* __restrict__ dst,
    unsigned short* __restrict__ bucket, int* __restrict__ cnt_s,
    int* __restrict__ cnt_d, int* __restrict__ ovf_cnt, int2* __restrict__ ovf, int nE) {
    __shared__ unsigned short bk[PNODES * CAP];  // 120 KB
    __shared__ unsigned int cur[PNODES];         // 5 KB (full in-degree count)
    __shared__ unsigned int hsrc[PNODES];        // 5 KB (out-degree count)
    const int nbeg = blockIdx.x * PNODES;
    for (int i = threadIdx.x; i < PNODES; i += 1024) { cur[i] = 0u; hsrc[i] = 0u; }
    __syncthreads();
    for (int e = (int)threadIdx.x; e < nE; e += 1024) {
        int s = src[e];
        int d = dst[e];
        unsigned ss = (unsigned)(s - nbeg);
        unsigned dd = (unsigned)(d - nbeg);
        if (ss < PNODES) atomicAdd(&hsrc[ss], 1u);
        if (dd < PNODES) {
            unsigned q = atomicAdd(&cur[dd], 1u);
            if (q < CAP) {
                bk[dd * CAP + q] = (unsigned short)s;
            } else {
                int o = atomicAdd(ovf_cnt, 1);
                if (o < OVF_CAP) ovf[o] = make_int2(d, s);
            }
        }
    }
    __syncthreads();
    // dense coalesced writeout: bucket region (120 KB), cnt_d, cnt_s
    uint4* gb = (uint4*)(bucket + (size_t)nbeg * CAP);
    const uint4* lb = (const uint4*)bk;
    const int n16 = PNODES * CAP * 2 / 16;   // 7500 uint4
    for (int i = threadIdx.x; i < n16; i += 1024) gb[i] = lb[i];
    for (int i = threadIdx.x; i < PNODES; i += 1024) {
        cnt_d[nbeg + i] = (int)cur[i];
        cnt_s[nbeg + i] = (int)hsrc[i];
    }
}

// ---------------- fused: rs arrays + xs = bf16(x * rs_out), ROW-MAJOR ----------------
__global__ void prescale_kernel(const float4* __restrict__ x, const int* __restrict__ cnt_s,
                                const int* __restrict__ cnt_d,
                                float* __restrict__ rs_out, float* __restrict__ rs_in,
                                ushort4* __restrict__ xs4, int nN) {
    int node = blockIdx.x * 8 + (threadIdx.x >> 5);
    int c = threadIdx.x & 31;
    if (node >= nN) return;
    float rs_o = 0.0f;
    if (c == 0) {
        rs_o = rsqrtf(fmaxf((float)cnt_s[node], 1.0f));
        rs_out[node] = rs_o;
        rs_in[node] = rsqrtf(fmaxf((float)cnt_d[node], 1.0f));
    }
    rs_o = __shfl(rs_o, threadIdx.x & 32);  // broadcast from node's lane 0 / 32
    float4 v = x[(size_t)node * 32 + c];
    ushort4 o;
    o.x = f2bf(v.x * rs_o);
    o.y = f2bf(v.y * rs_o);
    o.z = f2bf(v.z * rs_o);
    o.w = f2bf(v.w * rs_o);
    xs4[(size_t)node * 32 + c] = o;   // row-major: node row = 256 B
}

// ---------------- full-row gather over bucket CSR: 16 lanes/node, uint4 loads ----------------
__global__ void gather_kernel(const uint4* __restrict__ xs,   // bf16 row-major: 16 uint4/row
                              const int* __restrict__ cnt_d,
                              const unsigned short* __restrict__ bucket,
                              float4* __restrict__ msg4, int nN) {
    int node = blockIdx.x * 16 + ((int)threadIdx.x >> 4);
    int lane = threadIdx.x & 15;      // 16 B chunk index: cols [lane*8, lane*8+8)
    if (node >= nN) return;
    const unsigned short* bk = bucket + (size_t)node * CAP;
    int cnt = min(cnt_d[node], CAP);
    float a[8];
#pragma unroll
    for (int k = 0; k < 8; k++) a[k] = 0.f;
#define ACC8(v)                                              \
    a[0] += u2f_lo(v.x); a[1] += u2f_hi(v.x);                \
    a[2] += u2f_lo(v.y); a[3] += u2f_hi(v.y);                \
    a[4] += u2f_lo(v.z); a[5] += u2f_hi(v.z);                \
    a[6] += u2f_lo(v.w); a[7] += u2f_hi(v.w);
    int e = 0;
    for (; e + 3 < cnt; e += 4) {
        int s0 = bk[e], s1 = bk[e + 1], s2 = bk[e + 2], s3 = bk[e + 3];
        uint4 v0 = xs[(size_t)s0 * 16 + lane];
        uint4 v1 = xs[(size_t)s1 * 16 + lane];
        uint4 v2 = xs[(size_t)s2 * 16 + lane];
        uint4 v3 = xs[(size_t)s3 * 16 + lane];
        ACC8(v0) ACC8(v1) ACC8(v2) ACC8(v3)
    }
    for (; e < cnt; e++) {
        int s0 = bk[e];
        uint4 v0 = xs[(size_t)s0 * 16 + lane];
        ACC8(v0)
    }
#undef ACC8
    size_t o = (size_t)node * 32 + lane * 2;   // f32 row = 32 float4
    msg4[o]     = make_float4(a[0], a[1], a[2], a[3]);
    msg4[o + 1] = make_float4(a[4], a[5], a[6], a[7]);
}

// ---------------- overflow fixup (no-op when ovf_cnt==0; exact replay otherwise) ----------------
__global__ void ovf_kernel(const int2* __restrict__ ovf, const int* __restrict__ ovf_cnt,
                           const ushort4* __restrict__ xs4, float* __restrict__ msg) {
    int n = min(*ovf_cnt, OVF_CAP);
    int lane = threadIdx.x & 31;            // 32 lanes x 4 cols = 128
    for (int i = (int)(threadIdx.x >> 5); i < n; i += 8) {
        int2 ds = ovf[i];
        ushort4 v = xs4[(size_t)ds.y * 32 + lane];
        float* m = msg + (size_t)ds.x * D + lane * 4;
        atomicAdd(m + 0, bf2f(v.x));
        atomicAdd(m + 1, bf2f(v.y));
        atomicAdd(m + 2, bf2f(v.z));
        atomicAdd(m + 3, bf2f(v.w));
    }
}

// ---------------- W hi/lo split into MFMA B-fragment layout ----------------
// Wf layout: [hi | lo], each 2048 frags of short8. frag index flat = (ks*8+c)*64+lane;
// element j: B[k = ks*32 + (lane>>4)*8 + j][n = c*16 + (lane&15)]  (B = W, K x N row-major).
__global__ void wsplit_kernel(const float* __restrict__ W1, bf16_t* __restrict__ Wf1,
                              const float* __restrict__ W2, bf16_t* __restrict__ Wf2) {
    const float* W = blockIdx.y ? W2 : W1;
    bf16_t* Wf = blockIdx.y ? Wf2 : Wf1;
    int flat = blockIdx.x * 256 + (int)threadIdx.x;   // 0..2047 (grid.x = 8)
    int lane = flat & 63;
    int c = (flat >> 6) & 7;
    int ks = flat >> 9;
    int n = c * 16 + (lane & 15);
    int kb = ks * 32 + (lane >> 4) * 8;
#pragma unroll
    for (int j = 0; j < 8; j++) {
        float w = W[(size_t)(kb + j) * D + n];
        bf16_t hi = f2bf(w);
        bf16_t lo = f2bf(w - bf2f(hi));
        Wf[(size_t)flat * 8 + j] = hi;
        Wf[(size_t)(2048 + flat) * 8 + j] = lo;
    }
}

// ---------------- MFMA dense layer: split-bf16 (3-term Markidis) ----------------
// Per wave: 16 nodes x 128 cols, K=128. a = ah + al (bf16 split, in-register);
// w = wh + wl (pre-split). a*w ~= ah*wh + al*wh + ah*wl; dropped al*wl ~ 2^-18 rel.
// Fragment maps (guide §3, HW-verified): A: lane holds A[lane&15][(lane>>4)*8+j];
// B: lane holds B[(lane>>4)*8+j][lane&15]; C/D: col=lane&15, row=(lane>>4)*4+reg.
template <bool RELU_OUTSCALE, bool OUT_BF16>
__global__ __launch_bounds__(256) void gemm_mfma_kernel(
    const float* __restrict__ msg, const float* __restrict__ rs_in,
    const float* __restrict__ rs_out, const bf16_t* __restrict__ Wf,
    const float* __restrict__ bias, void* __restrict__ outp, int nN) {
    int lane = (int)threadIdx.x & 63;
    int wave = (int)threadIdx.x >> 6;
    int n0 = blockIdx.x * 64 + wave * 16;   // wave's 16-node tile
    int ar = lane & 15;                     // A row within tile
    int kg = lane >> 4;                     // k-subchunk of 8

    // ---- load A rows from global, split to bf16 hi/lo in-register ----
    short8v ahi[4], alo[4];
    {
        const float* ap = msg + (size_t)(n0 + ar) * D + kg * 8;
        bool valid = (n0 + ar) < nN;
#pragma unroll
        for (int ks = 0; ks < 4; ks++) {
            float av[8];
            if (valid) {
                float4 p0 = *(const float4*)(ap + ks * 32);
                float4 p1 = *(const float4*)(ap + ks * 32 + 4);
                av[0] = p0.x; av[1] = p0.y; av[2] = p0.z; av[3] = p0.w;
                av[4] = p1.x; av[5] = p1.y; av[6] = p1.z; av[7] = p1.w;
            } else {
#pragma unroll
                for (int j = 0; j < 8; j++) av[j] = 0.f;
            }
#pragma unroll
            for (int j = 0; j < 8; j++) {
                bf16_t h = f2bf(av[j]);
                bf16_t l = f2bf(av[j] - bf2f(h));
                ahi[ks][j] = (short)h;
                alo[ks][j] = (short)l;
            }
        }
    }

    f32x4 acc[8];
#pragma unroll
    for (int c = 0; c < 8; c++) acc[c] = (f32x4){0.f, 0.f, 0.f, 0.f};

    const short8v* Bh = (const short8v*)Wf;        // 2048 hi frags
    const short8v* Bl = Bh + 2048;                 // 2048 lo frags
#pragma unroll
    for (int ks = 0; ks < 4; ks++) {
#pragma unroll
        for (int c = 0; c < 8; c++) {
            int off = (ks * 8 + c) * 64 + lane;
            short8v wh = Bh[off];
            short8v wl = Bl[off];
            acc[c] = __builtin_amdgcn_mfma_f32_16x16x32_bf16(ahi[ks], wh, acc[c], 0, 0, 0);
            acc[c] = __builtin_amdgcn_mfma_f32_16x16x32_bf16(alo[ks], wh, acc[c], 0, 0, 0);
            acc[c] = __builtin_amdgcn_mfma_f32_16x16x32_bf16(ahi[ks], wl, acc[c], 0, 0, 0);
        }
    }

    // ---- epilogue: col = c*16 + (lane&15), node = n0 + kg*4 + r ----
    int ocol = lane & 15;
#pragma unroll
    for (int r = 0; r < 4; r++) {
        int node = n0 + kg * 4 + r;
        if (node >= nN) continue;
        float ri = rs_in[node];
        float ro = RELU_OUTSCALE ? rs_out[node] : 1.0f;
#pragma unroll
        for (int c = 0; c < 8; c++) {
            float v = acc[c][r] * ri + bias[c * 16 + ocol];
            if (RELU_OUTSCALE) v = fmaxf(v, 0.0f) * ro;
            if (OUT_BF16) {
                ((bf16_t*)outp)[(size_t)node * D + c * 16 + ocol] = f2bf(v);
            } else {
                ((float*)outp)[(size_t)node * D + c * 16 + ocol] = v;
            }
        }
    }
}

static inline size_t align16(size_t x) { return (x + 15) & ~(size_t)15; }

extern "C" void kernel_launch(void* const* d_in, const int* in_sizes, int n_in,
                              void* d_out, int out_size, void* d_ws, size_t ws_size,
                              hipStream_t stream) {
    const float* x   = (const float*)d_in[0];
    const int*   src = (const int*)d_in[1];
    const int*   dst = (const int*)d_in[2];
    const float* W1  = (const float*)d_in[3];
    const float* b1  = (const float*)d_in[4];
    const float* W2  = (const float*)d_in[5];
    const float* b2  = (const float*)d_in[6];
    float* out = (float*)d_out;

    // workspace layout. xs aliases hs (both row-major bf16).
    char* p = (char*)d_ws;
    float*          msg     = (float*)p;          p += align16((size_t)N_NODES * D * sizeof(float));
    int*            cnt_s   = (int*)p;            p += align16(N_NODES * sizeof(int));
    int*            cnt_d   = (int*)p;            p += align16(N_NODES * sizeof(int));
    int*            ovf_cnt = (int*)p;            p += align16(16 * sizeof(int));
    int2*           ovf     = (int2*)p;           p += align16((size_t)OVF_CAP * sizeof(int2));
    unsigned short* bucket  = (unsigned short*)p; p += align16((size_t)N_NODES * CAP * sizeof(unsigned short));
    float*          rs_out  = (float*)p;          p += align16(N_NODES * sizeof(float));
    float*          rs_in   = (float*)p;          p += align16(N_NODES * sizeof(float));
    bf16_t*         Wf1     = (bf16_t*)p;         p += align16((size_t)2 * 2048 * 8 * sizeof(bf16_t));
    bf16_t*         Wf2     = (bf16_t*)p;         p += align16((size_t)2 * 2048 * 8 * sizeof(bf16_t));
    bf16_t*         xs      = (bf16_t*)p;         // row-major bf16, aliased with hs (12.8 MB)
    bf16_t*         hs      = xs;

    // zero overflow counter only
    hipMemsetAsync(ovf_cnt, 0, 16 * sizeof(int), stream);

    // weight hi/lo split into MFMA fragment layout (both layers, one tiny launch)
    wsplit_kernel<<<dim3(8, 2), 256, 0, stream>>>(W1, Wf1, W2, Wf2);

    // single-kernel LDS-resident scatter: bucket CSR + cnt_s + cnt_d
    scatter_kernel<<<NPART, 1024, 0, stream>>>(src, dst, bucket, cnt_s, cnt_d,
                                               ovf_cnt, ovf, N_EDGES);

    // rs arrays + xs = bf16(x * rs_out), row-major
    prescale_kernel<<<(N_NODES + 7) / 8, 256, 0, stream>>>((const float4*)x, cnt_s, cnt_d,
                                                           rs_out, rs_in, (ushort4*)xs, N_NODES);

    int ggrid = (N_NODES + 15) / 16;   // 16 nodes per block
    int mgrid = (N_NODES + 63) / 64;   // 64 nodes per MFMA-GEMM block

    // layer 1 aggregation: msg = sum xs[s]
    gather_kernel<<<ggrid, 256, 0, stream>>>((const uint4*)xs, cnt_d, bucket,
                                             (float4*)msg, N_NODES);
    ovf_kernel<<<1, 256, 0, stream>>>(ovf, ovf_cnt, (const ushort4*)xs, msg);

    // layer 1 dense: hs = bf16( relu(rs_in * (msg @ W1) + b1) * rs_out ), row-major
    gemm_mfma_kernel<true, true><<<mgrid, 256, 0, stream>>>(
        msg, rs_in, rs_out, Wf1, b1, hs, N_NODES);

    // layer 2 aggregation: msg = sum hs[s]
    gather_kernel<<<ggrid, 256, 0, stream>>>((const uint4*)hs, cnt_d, bucket,
                                             (float4*)msg, N_NODES);
    ovf_kernel<<<1, 256, 0, stream>>>(ovf, ovf_cnt, (const ushort4*)hs, msg);

    // layer 2 dense: out = rs_in * (msg @ W2) + b2  (fp32 row-major)
    gemm_mfma_kernel<false, false><<<mgrid, 256, 0, stream>>>(
        msg, rs_in, nullptr, Wf2, b2, out, N_NODES);
}

// Round 7
// 225.382 us; speedup vs baseline: 2.2866x; 2.2866x over previous
//
#include <hip/hip_runtime.h>

#define N_NODES 50000
#define N_EDGES 800000
#define D 128
#define CAP 48      // bucket capacity per dst node (max in-degree ~45 for this dataset)
#define OVF_CAP 4096

#define BINS 40     // dst partitions (one scatter2 block each)
#define PNODES 1250 // nodes per partition = 50000/40
#define B1 64       // binning blocks (hist40/place40 share chunking)
#define CH1 ((N_EDGES + B1 - 1) / B1)   // 12500 edges per chunk
#define NW (N_NODES / 4)                // packed byte-counter words = 12500

typedef unsigned short bf16_t;
typedef __attribute__((ext_vector_type(8))) short short8v;   // 8 bf16 = 4 VGPR (MFMA A/B frag)
typedef __attribute__((ext_vector_type(4))) float f32x4;     // MFMA C/D frag

__device__ inline float bf2f(bf16_t u) {
    union { unsigned int i; float f; } v;
    v.i = ((unsigned int)u) << 16;
    return v.f;
}
__device__ inline bf16_t f2bf(float f) {
    union { float f; unsigned int i; } v;
    v.f = f;
    unsigned int u = v.i;
    unsigned int r = (u + 0x7FFFu + ((u >> 16) & 1u)) >> 16;  // RNE
    return (bf16_t)r;
}
// bf16 pair packed in a u32 (little-endian: lo half = even col, hi half = odd col)
__device__ inline float u2f_lo(unsigned int u) {
    union { unsigned int i; float f; } x; x.i = u << 16; return x.f;
}
__device__ inline float u2f_hi(unsigned int u) {
    union { unsigned int i; float f; } x; x.i = u & 0xFFFF0000u; return x.f;
}

// =============== two-phase binned scatter ===============
// Evidence trail: global atomics = ~51 MB memory-side writes (r0-2);
// 50000-stream scattered 2 B stores = ~51 MB partial-line thrash (r3-5 place);
// 40x full-edge-replay into LDS = latency-bound 350 us (r6).
// Fix: counting-sort edges into 40 COARSE bins (40 write streams -> interior
// lines fully written, ~50 KB dirty/block, no thrash), then 40 blocks each
// build their 1250-node bucket region in LDS from a CONTIGUOUS 80 KB segment
// and write out dense. Zero global atomics, no full-list replay.

// ---- hist40: per-chunk 40-bin dst histogram + fused src SWAR histogram ----
__global__ __launch_bounds__(1024) void hist40_kernel(const int* __restrict__ src,
                                                      const int* __restrict__ dst,
                                                      unsigned int* __restrict__ H40,
                                                      unsigned int* __restrict__ SH, int nE) {
    __shared__ unsigned int hb[BINS];
    __shared__ unsigned int hs[NW];   // 50 KB src byte counters
    for (int i = threadIdx.x; i < NW; i += 1024) hs[i] = 0u;
    if (threadIdx.x < BINS) hb[threadIdx.x] = 0u;
    __syncthreads();
    int e0 = blockIdx.x * CH1;
    int e1 = min(e0 + CH1, nE);
    for (int e = e0 + (int)threadIdx.x; e < e1; e += 1024) {
        int s = src[e];
        int d = dst[e];
        atomicAdd(&hs[s >> 2], 1u << (8 * (s & 3)));   // per-chunk count <= out-degree < 256
        atomicAdd(&hb[d / PNODES], 1u);
    }
    __syncthreads();
    if (threadIdx.x < BINS) H40[blockIdx.x * BINS + threadIdx.x] = hb[threadIdx.x];
    unsigned int* SHb = SH + (size_t)blockIdx.x * NW;
    for (int i = threadIdx.x; i < NW; i += 1024) SHb[i] = hs[i];
}

// ---- scan40: exclusive offsets per (chunk, bin) + bin bases/totals ----
__global__ void scan40_kernel(const unsigned int* __restrict__ H40,
                              unsigned int* __restrict__ OFF40,
                              unsigned int* __restrict__ binBase,
                              unsigned int* __restrict__ binTot) {
    __shared__ unsigned int part[B1 * BINS];   // 10 KB
    __shared__ unsigned int tot[BINS], base[BINS];
    int j = (int)threadIdx.x;
    if (j < BINS) {
        unsigned int run = 0;
        for (int b = 0; b < B1; b++) {
            part[b * BINS + j] = run;
            run += H40[b * BINS + j];
        }
        tot[j] = run;
    }
    __syncthreads();
    if (j == 0) {
        unsigned int run = 0;
        for (int q = 0; q < BINS; q++) { base[q] = run; run += tot[q]; }
    }
    __syncthreads();
    if (j < BINS) {
        binBase[j] = base[j];
        binTot[j] = tot[j];
        for (int b = 0; b < B1; b++) OFF40[b * BINS + j] = part[b * BINS + j] + base[j];
    }
}

// ---- place40: bin edges as (d_local | s<<16) into exclusive per-(chunk,bin) ranges ----
__global__ __launch_bounds__(1024) void place40_kernel(const int* __restrict__ src,
                                                       const int* __restrict__ dst,
                                                       const unsigned int* __restrict__ OFF40,
                                                       unsigned int* __restrict__ binned, int nE) {
    __shared__ unsigned int cur[BINS];
    if (threadIdx.x < BINS) cur[threadIdx.x] = OFF40[blockIdx.x * BINS + threadIdx.x];
    __syncthreads();
    int e0 = blockIdx.x * CH1;
    int e1 = min(e0 + CH1, nE);
    for (int e = e0 + (int)threadIdx.x; e < e1; e += 1024) {
        int s = src[e];
        int d = dst[e];
        int bin = d / PNODES;
        unsigned int pos = atomicAdd(&cur[bin], 1u);
        binned[pos] = (unsigned int)(d - bin * PNODES) | ((unsigned int)s << 16);
    }
}

// ---- sreduce: cnt_s = sum of per-chunk SWAR histograms ----
__global__ void sreduce_kernel(const unsigned int* __restrict__ SH, int* __restrict__ cnt_s) {
    int w = blockIdx.x * 256 + (int)threadIdx.x;
    if (w >= NW) return;
    unsigned int run = 0;
#pragma unroll 8
    for (int b = 0; b < B1; b++) run += SH[(size_t)b * NW + w];  // SWAR, total < 256/byte
    int4 c;
    c.x = (int)(run & 0xFFu); c.y = (int)((run >> 8) & 0xFFu);
    c.z = (int)((run >> 16) & 0xFFu); c.w = (int)(run >> 24);
    ((int4*)cnt_s)[w] = c;
}

// ---- scatter2: LDS-resident bucket build from contiguous bin segment ----
__global__ __launch_bounds__(1024) void scatter2_kernel(
    const unsigned int* __restrict__ binned, const unsigned int* __restrict__ binBase,
    const unsigned int* __restrict__ binTot, unsigned short* __restrict__ bucket,
    int* __restrict__ cnt_d, int* __restrict__ ovf_cnt, int2* __restrict__ ovf) {
    __shared__ unsigned short bk[PNODES * CAP];  // 120 KB
    __shared__ unsigned int cur[PNODES];         // 5 KB
    const int j = blockIdx.x;
    const int nbeg = j * PNODES;
    for (int i = threadIdx.x; i < PNODES; i += 1024) cur[i] = 0u;
    __syncthreads();
    unsigned int b0 = binBase[j];
    unsigned int n = binTot[j];
    for (unsigned int i = threadIdx.x; i < n; i += 1024) {
        unsigned int v = binned[b0 + i];
        unsigned int dl = v & 0xFFFFu;
        unsigned int s = v >> 16;
        unsigned int q = atomicAdd(&cur[dl], 1u);
        if (q < CAP) {
            bk[dl * CAP + q] = (unsigned short)s;
        } else {
            int o = atomicAdd(ovf_cnt, 1);
            if (o < OVF_CAP) ovf[o] = make_int2(nbeg + (int)dl, (int)s);
        }
    }
    __syncthreads();
    // dense coalesced writeout: bucket region (120 KB) + cnt_d
    uint4* gb = (uint4*)(bucket + (size_t)nbeg * CAP);
    const uint4* lb = (const uint4*)bk;
    const int n16 = PNODES * CAP * 2 / 16;   // 7500 uint4
    for (int i = threadIdx.x; i < n16; i += 1024) gb[i] = lb[i];
    for (int i = threadIdx.x; i < PNODES; i += 1024) cnt_d[nbeg + i] = (int)cur[i];
}

// ---------------- fused: rs arrays + xs = bf16(x * rs_out), ROW-MAJOR ----------------
__global__ void prescale_kernel(const float4* __restrict__ x, const int* __restrict__ cnt_s,
                                const int* __restrict__ cnt_d,
                                float* __restrict__ rs_out, float* __restrict__ rs_in,
                                ushort4* __restrict__ xs4, int nN) {
    int node = blockIdx.x * 8 + (threadIdx.x >> 5);
    int c = threadIdx.x & 31;
    if (node >= nN) return;
    float rs_o = 0.0f;
    if (c == 0) {
        rs_o = rsqrtf(fmaxf((float)cnt_s[node], 1.0f));
        rs_out[node] = rs_o;
        rs_in[node] = rsqrtf(fmaxf((float)cnt_d[node], 1.0f));
    }
    rs_o = __shfl(rs_o, threadIdx.x & 32);  // broadcast from node's lane 0 / 32
    float4 v = x[(size_t)node * 32 + c];
    ushort4 o;
    o.x = f2bf(v.x * rs_o);
    o.y = f2bf(v.y * rs_o);
    o.z = f2bf(v.z * rs_o);
    o.w = f2bf(v.w * rs_o);
    xs4[(size_t)node * 32 + c] = o;   // row-major: node row = 256 B
}

// ---------------- full-row gather over bucket CSR: 16 lanes/node, uint4 loads ----------------
__global__ void gather_kernel(const uint4* __restrict__ xs,   // bf16 row-major: 16 uint4/row
                              const int* __restrict__ cnt_d,
                              const unsigned short* __restrict__ bucket,
                              float4* __restrict__ msg4, int nN) {
    int node = blockIdx.x * 16 + ((int)threadIdx.x >> 4);
    int lane = threadIdx.x & 15;      // 16 B chunk index: cols [lane*8, lane*8+8)
    if (node >= nN) return;
    const unsigned short* bk = bucket + (size_t)node * CAP;
    int cnt = min(cnt_d[node], CAP);
    float a[8];
#pragma unroll
    for (int k = 0; k < 8; k++) a[k] = 0.f;
#define ACC8(v)                                              \
    a[0] += u2f_lo(v.x); a[1] += u2f_hi(v.x);                \
    a[2] += u2f_lo(v.y); a[3] += u2f_hi(v.y);                \
    a[4] += u2f_lo(v.z); a[5] += u2f_hi(v.z);                \
    a[6] += u2f_lo(v.w); a[7] += u2f_hi(v.w);
    int e = 0;
    for (; e + 3 < cnt; e += 4) {
        int s0 = bk[e], s1 = bk[e + 1], s2 = bk[e + 2], s3 = bk[e + 3];
        uint4 v0 = xs[(size_t)s0 * 16 + lane];
        uint4 v1 = xs[(size_t)s1 * 16 + lane];
        uint4 v2 = xs[(size_t)s2 * 16 + lane];
        uint4 v3 = xs[(size_t)s3 * 16 + lane];
        ACC8(v0) ACC8(v1) ACC8(v2) ACC8(v3)
    }
    for (; e < cnt; e++) {
        int s0 = bk[e];
        uint4 v0 = xs[(size_t)s0 * 16 + lane];
        ACC8(v0)
    }
#undef ACC8
    size_t o = (size_t)node * 32 + lane * 2;   // f32 row = 32 float4
    msg4[o]     = make_float4(a[0], a[1], a[2], a[3]);
    msg4[o + 1] = make_float4(a[4], a[5], a[6], a[7]);
}

// ---------------- overflow fixup (no-op when ovf_cnt==0; exact replay otherwise) ----------------
__global__ void ovf_kernel(const int2* __restrict__ ovf, const int* __restrict__ ovf_cnt,
                           const ushort4* __restrict__ xs4, float* __restrict__ msg) {
    int n = min(*ovf_cnt, OVF_CAP);
    int lane = threadIdx.x & 31;            // 32 lanes x 4 cols = 128
    for (int i = (int)(threadIdx.x >> 5); i < n; i += 8) {
        int2 ds = ovf[i];
        ushort4 v = xs4[(size_t)ds.y * 32 + lane];
        float* m = msg + (size_t)ds.x * D + lane * 4;
        atomicAdd(m + 0, bf2f(v.x));
        atomicAdd(m + 1, bf2f(v.y));
        atomicAdd(m + 2, bf2f(v.z));
        atomicAdd(m + 3, bf2f(v.w));
    }
}

// ---------------- W hi/lo split into MFMA B-fragment layout ----------------
// Wf layout: [hi | lo], each 2048 frags of short8. frag index flat = (ks*8+c)*64+lane;
// element j: B[k = ks*32 + (lane>>4)*8 + j][n = c*16 + (lane&15)]  (B = W, K x N row-major).
__global__ void wsplit_kernel(const float* __restrict__ W1, bf16_t* __restrict__ Wf1,
                              const float* __restrict__ W2, bf16_t* __restrict__ Wf2) {
    const float* W = blockIdx.y ? W2 : W1;
    bf16_t* Wf = blockIdx.y ? Wf2 : Wf1;
    int flat = blockIdx.x * 256 + (int)threadIdx.x;   // 0..2047 (grid.x = 8)
    int lane = flat & 63;
    int c = (flat >> 6) & 7;
    int ks = flat >> 9;
    int n = c * 16 + (lane & 15);
    int kb = ks * 32 + (lane >> 4) * 8;
#pragma unroll
    for (int j = 0; j < 8; j++) {
        float w = W[(size_t)(kb + j) * D + n];
        bf16_t hi = f2bf(w);
        bf16_t lo = f2bf(w - bf2f(hi));
        Wf[(size_t)flat * 8 + j] = hi;
        Wf[(size_t)(2048 + flat) * 8 + j] = lo;
    }
}

// ---------------- MFMA dense layer: split-bf16 (3-term Markidis) ----------------
// Per wave: 16 nodes x 128 cols, K=128. a = ah + al (bf16 split, in-register);
// w = wh + wl (pre-split). a*w ~= ah*wh + al*wh + ah*wl; dropped al*wl ~ 2^-18 rel.
// Fragment maps (guide §3, HW-verified): A: lane holds A[lane&15][(lane>>4)*8+j];
// B: lane holds B[(lane>>4)*8+j][lane&15]; C/D: col=lane&15, row=(lane>>4)*4+reg.
template <bool RELU_OUTSCALE, bool OUT_BF16>
__global__ __launch_bounds__(256) void gemm_mfma_kernel(
    const float* __restrict__ msg, const float* __restrict__ rs_in,
    const float* __restrict__ rs_out, const bf16_t* __restrict__ Wf,
    const float* __restrict__ bias, void* __restrict__ outp, int nN) {
    int lane = (int)threadIdx.x & 63;
    int wave = (int)threadIdx.x >> 6;
    int n0 = blockIdx.x * 64 + wave * 16;   // wave's 16-node tile
    int ar = lane & 15;                     // A row within tile
    int kg = lane >> 4;                     // k-subchunk of 8

    // ---- load A rows from global, split to bf16 hi/lo in-register ----
    short8v ahi[4], alo[4];
    {
        const float* ap = msg + (size_t)(n0 + ar) * D + kg * 8;
        bool valid = (n0 + ar) < nN;
#pragma unroll
        for (int ks = 0; ks < 4; ks++) {
            float av[8];
            if (valid) {
                float4 p0 = *(const float4*)(ap + ks * 32);
                float4 p1 = *(const float4*)(ap + ks * 32 + 4);
                av[0] = p0.x; av[1] = p0.y; av[2] = p0.z; av[3] = p0.w;
                av[4] = p1.x; av[5] = p1.y; av[6] = p1.z; av[7] = p1.w;
            } else {
#pragma unroll
                for (int j = 0; j < 8; j++) av[j] = 0.f;
            }
#pragma unroll
            for (int j = 0; j < 8; j++) {
                bf16_t h = f2bf(av[j]);
                bf16_t l = f2bf(av[j] - bf2f(h));
                ahi[ks][j] = (short)h;
                alo[ks][j] = (short)l;
            }
        }
    }

    f32x4 acc[8];
#pragma unroll
    for (int c = 0; c < 8; c++) acc[c] = (f32x4){0.f, 0.f, 0.f, 0.f};

    const short8v* Bh = (const short8v*)Wf;        // 2048 hi frags
    const short8v* Bl = Bh + 2048;                 // 2048 lo frags
#pragma unroll
    for (int ks = 0; ks < 4; ks++) {
#pragma unroll
        for (int c = 0; c < 8; c++) {
            int off = (ks * 8 + c) * 64 + lane;
            short8v wh = Bh[off];
            short8v wl = Bl[off];
            acc[c] = __builtin_amdgcn_mfma_f32_16x16x32_bf16(ahi[ks], wh, acc[c], 0, 0, 0);
            acc[c] = __builtin_amdgcn_mfma_f32_16x16x32_bf16(alo[ks], wh, acc[c], 0, 0, 0);
            acc[c] = __builtin_amdgcn_mfma_f32_16x16x32_bf16(ahi[ks], wl, acc[c], 0, 0, 0);
        }
    }

    // ---- epilogue: col = c*16 + (lane&15), node = n0 + kg*4 + r ----
    int ocol = lane & 15;
#pragma unroll
    for (int r = 0; r < 4; r++) {
        int node = n0 + kg * 4 + r;
        if (node >= nN) continue;
        float ri = rs_in[node];
        float ro = RELU_OUTSCALE ? rs_out[node] : 1.0f;
#pragma unroll
        for (int c = 0; c < 8; c++) {
            float v = acc[c][r] * ri + bias[c * 16 + ocol];
            if (RELU_OUTSCALE) v = fmaxf(v, 0.0f) * ro;
            if (OUT_BF16) {
                ((bf16_t*)outp)[(size_t)node * D + c * 16 + ocol] = f2bf(v);
            } else {
                ((float*)outp)[(size_t)node * D + c * 16 + ocol] = v;
            }
        }
    }
}

static inline size_t align16(size_t x) { return (x + 15) & ~(size_t)15; }

extern "C" void kernel_launch(void* const* d_in, const int* in_sizes, int n_in,
                              void* d_out, int out_size, void* d_ws, size_t ws_size,
                              hipStream_t stream) {
    const float* x   = (const float*)d_in[0];
    const int*   src = (const int*)d_in[1];
    const int*   dst = (const int*)d_in[2];
    const float* W1  = (const float*)d_in[3];
    const float* b1  = (const float*)d_in[4];
    const float* W2  = (const float*)d_in[5];
    const float* b2  = (const float*)d_in[6];
    float* out = (float*)d_out;

    // workspace layout. xs aliases hs (both row-major bf16).
    char* p = (char*)d_ws;
    float*          msg     = (float*)p;          p += align16((size_t)N_NODES * D * sizeof(float));
    int*            cnt_s   = (int*)p;            p += align16(N_NODES * sizeof(int));
    int*            cnt_d   = (int*)p;            p += align16(N_NODES * sizeof(int));
    int*            ovf_cnt = (int*)p;            p += align16(16 * sizeof(int));
    int2*           ovf     = (int2*)p;           p += align16((size_t)OVF_CAP * sizeof(int2));
    unsigned short* bucket  = (unsigned short*)p; p += align16((size_t)N_NODES * CAP * sizeof(unsigned short));
    float*          rs_out  = (float*)p;          p += align16(N_NODES * sizeof(float));
    float*          rs_in   = (float*)p;          p += align16(N_NODES * sizeof(float));
    bf16_t*         Wf1     = (bf16_t*)p;         p += align16((size_t)2 * 2048 * 8 * sizeof(bf16_t));
    bf16_t*         Wf2     = (bf16_t*)p;         p += align16((size_t)2 * 2048 * 8 * sizeof(bf16_t));
    unsigned int*   H40     = (unsigned int*)p;   p += align16((size_t)B1 * BINS * sizeof(unsigned int));
    unsigned int*   OFF40   = (unsigned int*)p;   p += align16((size_t)B1 * BINS * sizeof(unsigned int));
    unsigned int*   binBase = (unsigned int*)p;   p += align16(BINS * sizeof(unsigned int));
    unsigned int*   binTot  = (unsigned int*)p;   p += align16(BINS * sizeof(unsigned int));
    bf16_t*         xs      = (bf16_t*)p;         // row-major bf16, aliased with hs (12.8 MB)
    bf16_t*         hs      = xs;

    // binning scratch ALIASES msg (3.2 + 3.2 MB <= 25.6 MB); msg is fully
    // rewritten by gather_kernel after the binning pipeline completes.
    unsigned int* binned = (unsigned int*)msg;           // 800K u32 = 3.2 MB
    unsigned int* SH     = binned + N_EDGES;             // B1*NW u32 = 3.2 MB

    // zero overflow counter only
    hipMemsetAsync(ovf_cnt, 0, 16 * sizeof(int), stream);

    // weight hi/lo split into MFMA fragment layout (both layers, one tiny launch)
    wsplit_kernel<<<dim3(8, 2), 256, 0, stream>>>(W1, Wf1, W2, Wf2);

    // two-phase binned scatter
    hist40_kernel<<<B1, 1024, 0, stream>>>(src, dst, H40, SH, N_EDGES);
    scan40_kernel<<<1, 64, 0, stream>>>(H40, OFF40, binBase, binTot);
    place40_kernel<<<B1, 1024, 0, stream>>>(src, dst, OFF40, binned, N_EDGES);
    sreduce_kernel<<<(NW + 255) / 256, 256, 0, stream>>>(SH, cnt_s);
    scatter2_kernel<<<BINS, 1024, 0, stream>>>(binned, binBase, binTot, bucket,
                                               cnt_d, ovf_cnt, ovf);

    // rs arrays + xs = bf16(x * rs_out), row-major
    prescale_kernel<<<(N_NODES + 7) / 8, 256, 0, stream>>>((const float4*)x, cnt_s, cnt_d,
                                                           rs_out, rs_in, (ushort4*)xs, N_NODES);

    int ggrid = (N_NODES + 15) / 16;   // 16 nodes per block
    int mgrid = (N_NODES + 63) / 64;   // 64 nodes per MFMA-GEMM block

    // layer 1 aggregation: msg = sum xs[s]
    gather_kernel<<<ggrid, 256, 0, stream>>>((const uint4*)xs, cnt_d, bucket,
                                             (float4*)msg, N_NODES);
    ovf_kernel<<<1, 256, 0, stream>>>(ovf, ovf_cnt, (const ushort4*)xs, msg);

    // layer 1 dense: hs = bf16( relu(rs_in * (msg @ W1) + b1) * rs_out ), row-major
    gemm_mfma_kernel<true, true><<<mgrid, 256, 0, stream>>>(
        msg, rs_in, rs_out, Wf1, b1, hs, N_NODES);

    // layer 2 aggregation: msg = sum hs[s]
    gather_kernel<<<ggrid, 256, 0, stream>>>((const uint4*)hs, cnt_d, bucket,
                                             (float4*)msg, N_NODES);
    ovf_kernel<<<1, 256, 0, stream>>>(ovf, ovf_cnt, (const ushort4*)hs, msg);

    // layer 2 dense: out = rs_in * (msg @ W2) + b2  (fp32 row-major)
    gemm_mfma_kernel<false, false><<<mgrid, 256, 0, stream>>>(
        msg, rs_in, nullptr, Wf2, b2, out, N_NODES);
}

// Round 8
// 207.278 us; speedup vs baseline: 2.4863x; 1.0873x over previous
//
#include <hip/hip_runtime.h>

#define N_NODES 50000
#define N_EDGES 800000
#define D 128
#define CAP 48      // bucket capacity per dst node (max in-degree ~45 for this dataset)
#define OVF_CAP 4096

#define BINS 40     // dst partitions (one scatter2 block each)
#define PNODES 1250 // nodes per partition = 50000/40
#define B1 64       // binning blocks (hist40/place40 share chunking)
#define CH1 ((N_EDGES + B1 - 1) / B1)   // 12500 edges per chunk
#define NW (N_NODES / 4)                // packed byte-counter words = 12500

typedef unsigned short bf16_t;
typedef __attribute__((ext_vector_type(8))) short short8v;   // 8 bf16 = 4 VGPR (MFMA A/B frag)
typedef __attribute__((ext_vector_type(4))) float f32x4;     // MFMA C/D frag

__device__ inline float bf2f(bf16_t u) {
    union { unsigned int i; float f; } v;
    v.i = ((unsigned int)u) << 16;
    return v.f;
}
__device__ inline bf16_t f2bf(float f) {
    union { float f; unsigned int i; } v;
    v.f = f;
    unsigned int u = v.i;
    unsigned int r = (u + 0x7FFFu + ((u >> 16) & 1u)) >> 16;  // RNE
    return (bf16_t)r;
}
// bf16 pair packed in a u32 (little-endian: lo half = even col, hi half = odd col)
__device__ inline float u2f_lo(unsigned int u) {
    union { unsigned int i; float f; } x; x.i = u << 16; return x.f;
}
__device__ inline float u2f_hi(unsigned int u) {
    union { unsigned int i; float f; } x; x.i = u & 0xFFFF0000u; return x.f;
}

// =============== two-phase binned scatter (unchanged from r7, proven) ===============
__global__ __launch_bounds__(1024) void hist40_kernel(const int* __restrict__ src,
                                                      const int* __restrict__ dst,
                                                      unsigned int* __restrict__ H40,
                                                      unsigned int* __restrict__ SH, int nE) {
    __shared__ unsigned int hb[BINS];
    __shared__ unsigned int hs[NW];   // 50 KB src byte counters
    for (int i = threadIdx.x; i < NW; i += 1024) hs[i] = 0u;
    if (threadIdx.x < BINS) hb[threadIdx.x] = 0u;
    __syncthreads();
    int e0 = blockIdx.x * CH1;
    int e1 = min(e0 + CH1, nE);
    for (int e = e0 + (int)threadIdx.x; e < e1; e += 1024) {
        int s = src[e];
        int d = dst[e];
        atomicAdd(&hs[s >> 2], 1u << (8 * (s & 3)));   // per-chunk count <= out-degree < 256
        atomicAdd(&hb[d / PNODES], 1u);
    }
    __syncthreads();
    if (threadIdx.x < BINS) H40[blockIdx.x * BINS + threadIdx.x] = hb[threadIdx.x];
    unsigned int* SHb = SH + (size_t)blockIdx.x * NW;
    for (int i = threadIdx.x; i < NW; i += 1024) SHb[i] = hs[i];
}

__global__ void scan40_kernel(const unsigned int* __restrict__ H40,
                              unsigned int* __restrict__ OFF40,
                              unsigned int* __restrict__ binBase,
                              unsigned int* __restrict__ binTot) {
    __shared__ unsigned int part[B1 * BINS];   // 10 KB
    __shared__ unsigned int tot[BINS], base[BINS];
    int j = (int)threadIdx.x;
    if (j < BINS) {
        unsigned int run = 0;
        for (int b = 0; b < B1; b++) {
            part[b * BINS + j] = run;
            run += H40[b * BINS + j];
        }
        tot[j] = run;
    }
    __syncthreads();
    if (j == 0) {
        unsigned int run = 0;
        for (int q = 0; q < BINS; q++) { base[q] = run; run += tot[q]; }
    }
    __syncthreads();
    if (j < BINS) {
        binBase[j] = base[j];
        binTot[j] = tot[j];
        for (int b = 0; b < B1; b++) OFF40[b * BINS + j] = part[b * BINS + j] + base[j];
    }
}

__global__ __launch_bounds__(1024) void place40_kernel(const int* __restrict__ src,
                                                       const int* __restrict__ dst,
                                                       const unsigned int* __restrict__ OFF40,
                                                       unsigned int* __restrict__ binned, int nE) {
    __shared__ unsigned int cur[BINS];
    if (threadIdx.x < BINS) cur[threadIdx.x] = OFF40[blockIdx.x * BINS + threadIdx.x];
    __syncthreads();
    int e0 = blockIdx.x * CH1;
    int e1 = min(e0 + CH1, nE);
    for (int e = e0 + (int)threadIdx.x; e < e1; e += 1024) {
        int s = src[e];
        int d = dst[e];
        int bin = d / PNODES;
        unsigned int pos = atomicAdd(&cur[bin], 1u);
        binned[pos] = (unsigned int)(d - bin * PNODES) | ((unsigned int)s << 16);
    }
}

__global__ void sreduce_kernel(const unsigned int* __restrict__ SH, int* __restrict__ cnt_s) {
    int w = blockIdx.x * 256 + (int)threadIdx.x;
    if (w >= NW) return;
    unsigned int run = 0;
#pragma unroll 8
    for (int b = 0; b < B1; b++) run += SH[(size_t)b * NW + w];  // SWAR, total < 256/byte
    int4 c;
    c.x = (int)(run & 0xFFu); c.y = (int)((run >> 8) & 0xFFu);
    c.z = (int)((run >> 16) & 0xFFu); c.w = (int)(run >> 24);
    ((int4*)cnt_s)[w] = c;
}

__global__ __launch_bounds__(1024) void scatter2_kernel(
    const unsigned int* __restrict__ binned, const unsigned int* __restrict__ binBase,
    const unsigned int* __restrict__ binTot, unsigned short* __restrict__ bucket,
    int* __restrict__ cnt_d, int* __restrict__ ovf_cnt, int2* __restrict__ ovf) {
    __shared__ unsigned short bk[PNODES * CAP];  // 120 KB
    __shared__ unsigned int cur[PNODES];         // 5 KB
    const int j = blockIdx.x;
    const int nbeg = j * PNODES;
    for (int i = threadIdx.x; i < PNODES; i += 1024) cur[i] = 0u;
    __syncthreads();
    unsigned int b0 = binBase[j];
    unsigned int n = binTot[j];
    for (unsigned int i = threadIdx.x; i < n; i += 1024) {
        unsigned int v = binned[b0 + i];
        unsigned int dl = v & 0xFFFFu;
        unsigned int s = v >> 16;
        unsigned int q = atomicAdd(&cur[dl], 1u);
        if (q < CAP) {
            bk[dl * CAP + q] = (unsigned short)s;
        } else {
            int o = atomicAdd(ovf_cnt, 1);
            if (o < OVF_CAP) ovf[o] = make_int2(nbeg + (int)dl, (int)s);
        }
    }
    __syncthreads();
    uint4* gb = (uint4*)(bucket + (size_t)nbeg * CAP);
    const uint4* lb = (const uint4*)bk;
    const int n16 = PNODES * CAP * 2 / 16;   // 7500 uint4
    for (int i = threadIdx.x; i < n16; i += 1024) gb[i] = lb[i];
    for (int i = threadIdx.x; i < PNODES; i += 1024) cnt_d[nbeg + i] = (int)cur[i];
}

// ---------------- fused: rs arrays + xs = bf16(x * rs_out), ROW-MAJOR ----------------
__global__ void prescale_kernel(const float4* __restrict__ x, const int* __restrict__ cnt_s,
                                const int* __restrict__ cnt_d,
                                float* __restrict__ rs_out, float* __restrict__ rs_in,
                                ushort4* __restrict__ xs4, int nN) {
    int node = blockIdx.x * 8 + (threadIdx.x >> 5);
    int c = threadIdx.x & 31;
    if (node >= nN) return;
    float rs_o = 0.0f;
    if (c == 0) {
        rs_o = rsqrtf(fmaxf((float)cnt_s[node], 1.0f));
        rs_out[node] = rs_o;
        rs_in[node] = rsqrtf(fmaxf((float)cnt_d[node], 1.0f));
    }
    rs_o = __shfl(rs_o, threadIdx.x & 32);  // broadcast from node's lane 0 / 32
    float4 v = x[(size_t)node * 32 + c];
    ushort4 o;
    o.x = f2bf(v.x * rs_o);
    o.y = f2bf(v.y * rs_o);
    o.z = f2bf(v.z * rs_o);
    o.w = f2bf(v.w * rs_o);
    xs4[(size_t)node * 32 + c] = o;   // row-major: node row = 256 B
}

// ---------------- W hi/lo split into MFMA B-fragment layout ----------------
// Wf layout: [hi | lo], each 2048 frags of short8. frag index flat = (ks*8+c)*64+lane;
// element j: B[k = ks*32 + (lane>>4)*8 + j][n = c*16 + (lane&15)]  (B = W, K x N row-major).
__global__ void wsplit_kernel(const float* __restrict__ W1, bf16_t* __restrict__ Wf1,
                              const float* __restrict__ W2, bf16_t* __restrict__ Wf2) {
    const float* W = blockIdx.y ? W2 : W1;
    bf16_t* Wf = blockIdx.y ? Wf2 : Wf1;
    int flat = blockIdx.x * 256 + (int)threadIdx.x;   // 0..2047 (grid.x = 8)
    int lane = flat & 63;
    int c = (flat >> 6) & 7;
    int ks = flat >> 9;
    int n = c * 16 + (lane & 15);
    int kb = ks * 32 + (lane >> 4) * 8;
#pragma unroll
    for (int j = 0; j < 8; j++) {
        float w = W[(size_t)(kb + j) * D + n];
        bf16_t hi = f2bf(w);
        bf16_t lo = f2bf(w - bf2f(hi));
        Wf[(size_t)flat * 8 + j] = hi;
        Wf[(size_t)(2048 + flat) * 8 + j] = lo;
    }
}

// =============== fused gather + ovf-patch + MFMA gemm (one kernel per layer) ===============
// Phase 1: proven full-row gather (16 lanes/node, uint4, 4-way unroll) into a
// padded LDS tile sA[64][132] (pad -> 16-row stride spans 8 banks, 2-way = free).
// Overflow exactness: if *ovf_cnt > 0 (never, for this dataset), scan the ovf
// list and patch sA with LDS float atomics. Phase 2: proven split-bf16 MFMA
// (3-term Markidis) reading A from LDS. Kills the 2x25.6 MB msg round-trip and
// 2 launches per layer.
#define LDW 132
template <bool RELU_OUTSCALE, bool OUT_BF16>
__global__ __launch_bounds__(256) void fused_layer_kernel(
    const uint4* __restrict__ xsrc,          // bf16 row-major src features: 16 uint4/row
    const int* __restrict__ cnt_d,
    const unsigned short* __restrict__ bucket,
    const int* __restrict__ ovf_cnt, const int2* __restrict__ ovf,
    const float* __restrict__ rs_in, const float* __restrict__ rs_out,
    const bf16_t* __restrict__ Wf, const float* __restrict__ bias,
    void* __restrict__ outp, int nN) {
    __shared__ float sA[64 * LDW];   // 33.8 KB
    int tid = (int)threadIdx.x;
    int n0 = blockIdx.x * 64;
    int lane16 = tid & 15;
    int grp = tid >> 4;        // 0..15

    // ---- phase 1: gather 64 node rows into sA ----
#define ACC8(v)                                              \
    a[0] += u2f_lo(v.x); a[1] += u2f_hi(v.x);                \
    a[2] += u2f_lo(v.y); a[3] += u2f_hi(v.y);                \
    a[4] += u2f_lo(v.z); a[5] += u2f_hi(v.z);                \
    a[6] += u2f_lo(v.w); a[7] += u2f_hi(v.w);
#pragma unroll
    for (int r = 0; r < 4; r++) {
        int ln = r * 16 + grp;     // local node 0..63
        int node = n0 + ln;
        float a[8];
#pragma unroll
        for (int k = 0; k < 8; k++) a[k] = 0.f;
        if (node < nN) {
            const unsigned short* bk = bucket + (size_t)node * CAP;
            int cnt = min(cnt_d[node], CAP);
            int e = 0;
            for (; e + 3 < cnt; e += 4) {
                int s0 = bk[e], s1 = bk[e + 1], s2 = bk[e + 2], s3 = bk[e + 3];
                uint4 v0 = xsrc[(size_t)s0 * 16 + lane16];
                uint4 v1 = xsrc[(size_t)s1 * 16 + lane16];
                uint4 v2 = xsrc[(size_t)s2 * 16 + lane16];
                uint4 v3 = xsrc[(size_t)s3 * 16 + lane16];
                ACC8(v0) ACC8(v1) ACC8(v2) ACC8(v3)
            }
            for (; e < cnt; e++) {
                int s0 = bk[e];
                uint4 v0 = xsrc[(size_t)s0 * 16 + lane16];
                ACC8(v0)
            }
        }
        float* row = sA + ln * LDW + lane16 * 8;
#pragma unroll
        for (int k = 0; k < 8; k++) row[k] = a[k];
    }
#undef ACC8

    // ---- overflow patch (uniform branch; no-op when list empty) ----
    int novf = min(*ovf_cnt, OVF_CAP);
    if (novf > 0) {
        __syncthreads();
        for (int i = tid; i < novf; i += 256) {
            int2 ds = ovf[i];
            int ln = ds.x - n0;
            if ((unsigned)ln < 64u) {
                const uint4* xr = xsrc + (size_t)ds.y * 16;
                for (int c = 0; c < 16; c++) {
                    uint4 v = xr[c];
                    float* q = sA + ln * LDW + c * 8;
                    atomicAdd(q + 0, u2f_lo(v.x)); atomicAdd(q + 1, u2f_hi(v.x));
                    atomicAdd(q + 2, u2f_lo(v.y)); atomicAdd(q + 3, u2f_hi(v.y));
                    atomicAdd(q + 4, u2f_lo(v.z)); atomicAdd(q + 5, u2f_hi(v.z));
                    atomicAdd(q + 6, u2f_lo(v.w)); atomicAdd(q + 7, u2f_hi(v.w));
                }
            }
        }
    }
    __syncthreads();

    // ---- phase 2: split-bf16 MFMA from LDS ----
    int lane = tid & 63;
    int wave = tid >> 6;
    int ar = lane & 15;                     // A row within 16-node tile
    int kg = lane >> 4;                     // k-subchunk of 8
    const float* ap = sA + (wave * 16 + ar) * LDW + kg * 8;
    short8v ahi[4], alo[4];
#pragma unroll
    for (int ks = 0; ks < 4; ks++) {
#pragma unroll
        for (int j = 0; j < 8; j++) {
            float av = ap[ks * 32 + j];
            bf16_t h = f2bf(av);
            ahi[ks][j] = (short)h;
            alo[ks][j] = (short)f2bf(av - bf2f(h));
        }
    }

    f32x4 acc[8];
#pragma unroll
    for (int c = 0; c < 8; c++) acc[c] = (f32x4){0.f, 0.f, 0.f, 0.f};

    const short8v* Bh = (const short8v*)Wf;        // 2048 hi frags
    const short8v* Bl = Bh + 2048;                 // 2048 lo frags
#pragma unroll
    for (int ks = 0; ks < 4; ks++) {
#pragma unroll
        for (int c = 0; c < 8; c++) {
            int off = (ks * 8 + c) * 64 + lane;
            short8v wh = Bh[off];
            short8v wl = Bl[off];
            acc[c] = __builtin_amdgcn_mfma_f32_16x16x32_bf16(ahi[ks], wh, acc[c], 0, 0, 0);
            acc[c] = __builtin_amdgcn_mfma_f32_16x16x32_bf16(alo[ks], wh, acc[c], 0, 0, 0);
            acc[c] = __builtin_amdgcn_mfma_f32_16x16x32_bf16(ahi[ks], wl, acc[c], 0, 0, 0);
        }
    }

    // ---- epilogue: col = c*16 + (lane&15), node = n0 + wave*16 + kg*4 + r ----
    int ocol = lane & 15;
#pragma unroll
    for (int r = 0; r < 4; r++) {
        int node = n0 + wave * 16 + kg * 4 + r;
        if (node >= nN) continue;
        float ri = rs_in[node];
        float ro = RELU_OUTSCALE ? rs_out[node] : 1.0f;
#pragma unroll
        for (int c = 0; c < 8; c++) {
            float v = acc[c][r] * ri + bias[c * 16 + ocol];
            if (RELU_OUTSCALE) v = fmaxf(v, 0.0f) * ro;
            if (OUT_BF16) {
                ((bf16_t*)outp)[(size_t)node * D + c * 16 + ocol] = f2bf(v);
            } else {
                ((float*)outp)[(size_t)node * D + c * 16 + ocol] = v;
            }
        }
    }
}
#undef LDW

static inline size_t align16(size_t x) { return (x + 15) & ~(size_t)15; }

extern "C" void kernel_launch(void* const* d_in, const int* in_sizes, int n_in,
                              void* d_out, int out_size, void* d_ws, size_t ws_size,
                              hipStream_t stream) {
    const float* x   = (const float*)d_in[0];
    const int*   src = (const int*)d_in[1];
    const int*   dst = (const int*)d_in[2];
    const float* W1  = (const float*)d_in[3];
    const float* b1  = (const float*)d_in[4];
    const float* W2  = (const float*)d_in[5];
    const float* b2  = (const float*)d_in[6];
    float* out = (float*)d_out;

    // workspace layout. NOTE: hs no longer aliases xs (fused kernel reads xs
    // while writing hs); msg buffer is gone entirely.
    char* p = (char*)d_ws;
    int*            cnt_s   = (int*)p;            p += align16(N_NODES * sizeof(int));
    int*            cnt_d   = (int*)p;            p += align16(N_NODES * sizeof(int));
    int*            ovf_cnt = (int*)p;            p += align16(16 * sizeof(int));
    int2*           ovf     = (int2*)p;           p += align16((size_t)OVF_CAP * sizeof(int2));
    unsigned short* bucket  = (unsigned short*)p; p += align16((size_t)N_NODES * CAP * sizeof(unsigned short));
    float*          rs_out  = (float*)p;          p += align16(N_NODES * sizeof(float));
    float*          rs_in   = (float*)p;          p += align16(N_NODES * sizeof(float));
    bf16_t*         Wf1     = (bf16_t*)p;         p += align16((size_t)2 * 2048 * 8 * sizeof(bf16_t));
    bf16_t*         Wf2     = (bf16_t*)p;         p += align16((size_t)2 * 2048 * 8 * sizeof(bf16_t));
    unsigned int*   H40     = (unsigned int*)p;   p += align16((size_t)B1 * BINS * sizeof(unsigned int));
    unsigned int*   OFF40   = (unsigned int*)p;   p += align16((size_t)B1 * BINS * sizeof(unsigned int));
    unsigned int*   binBase = (unsigned int*)p;   p += align16(BINS * sizeof(unsigned int));
    unsigned int*   binTot  = (unsigned int*)p;   p += align16(BINS * sizeof(unsigned int));
    unsigned int*   binned  = (unsigned int*)p;   p += align16((size_t)N_EDGES * sizeof(unsigned int));
    unsigned int*   SH      = (unsigned int*)p;   p += align16((size_t)B1 * NW * sizeof(unsigned int));
    bf16_t*         xs      = (bf16_t*)p;         p += align16((size_t)N_NODES * D * sizeof(bf16_t));
    bf16_t*         hs      = (bf16_t*)p;         // separate 12.8 MB buffer

    // zero overflow counter only
    hipMemsetAsync(ovf_cnt, 0, 16 * sizeof(int), stream);

    // weight hi/lo split into MFMA fragment layout (both layers, one tiny launch)
    wsplit_kernel<<<dim3(8, 2), 256, 0, stream>>>(W1, Wf1, W2, Wf2);

    // two-phase binned scatter
    hist40_kernel<<<B1, 1024, 0, stream>>>(src, dst, H40, SH, N_EDGES);
    scan40_kernel<<<1, 64, 0, stream>>>(H40, OFF40, binBase, binTot);
    place40_kernel<<<B1, 1024, 0, stream>>>(src, dst, OFF40, binned, N_EDGES);
    sreduce_kernel<<<(NW + 255) / 256, 256, 0, stream>>>(SH, cnt_s);
    scatter2_kernel<<<BINS, 1024, 0, stream>>>(binned, binBase, binTot, bucket,
                                               cnt_d, ovf_cnt, ovf);

    // rs arrays + xs = bf16(x * rs_out), row-major
    prescale_kernel<<<(N_NODES + 7) / 8, 256, 0, stream>>>((const float4*)x, cnt_s, cnt_d,
                                                           rs_out, rs_in, (ushort4*)xs, N_NODES);

    int fgrid = (N_NODES + 63) / 64;   // 64 nodes per fused block

    // layer 1: hs = bf16( relu(rs_in * (gather(xs) @ W1) + b1) * rs_out )
    fused_layer_kernel<true, true><<<fgrid, 256, 0, stream>>>(
        (const uint4*)xs, cnt_d, bucket, ovf_cnt, ovf, rs_in, rs_out, Wf1, b1, hs, N_NODES);

    // layer 2: out = rs_in * (gather(hs) @ W2) + b2   (fp32 row-major)
    fused_layer_kernel<false, false><<<fgrid, 256, 0, stream>>>(
        (const uint4*)hs, cnt_d, bucket, ovf_cnt, ovf, rs_in, rs_out, Wf2, b2, out, N_NODES);
}

// Round 9
// 197.256 us; speedup vs baseline: 2.6127x; 1.0508x over previous
//
#include <hip/hip_runtime.h>

#define N_NODES 50000
#define N_EDGES 800000
#define D 128
#define CAP 48      // bucket capacity per dst node (max in-degree ~45 for this dataset)
#define OVF_CAP 4096

#define BINS 40     // dst partitions (one scatter2 block each)
#define PNODES 1250 // nodes per partition = 50000/40
#define B1 64       // binning blocks (hist40/place40 share chunking)
#define CH1 ((N_EDGES + B1 - 1) / B1)   // 12500 edges per chunk
#define NW (N_NODES / 4)                // packed byte-counter words = 12500
#define WPB ((NW + B1 - 1) / B1)        // sreduce words per place40 block = 196

typedef unsigned short bf16_t;
typedef __attribute__((ext_vector_type(8))) short short8v;   // 8 bf16 = 4 VGPR (MFMA A/B frag)
typedef __attribute__((ext_vector_type(4))) float f32x4;     // MFMA C/D frag

__device__ inline float bf2f(bf16_t u) {
    union { unsigned int i; float f; } v;
    v.i = ((unsigned int)u) << 16;
    return v.f;
}
__device__ inline bf16_t f2bf(float f) {
    union { float f; unsigned int i; } v;
    v.f = f;
    unsigned int u = v.i;
    unsigned int r = (u + 0x7FFFu + ((u >> 16) & 1u)) >> 16;  // RNE
    return (bf16_t)r;
}
// bf16 pair packed in a u32 (little-endian: lo half = even col, hi half = odd col)
__device__ inline float u2f_lo(unsigned int u) {
    union { unsigned int i; float f; } x; x.i = u << 16; return x.f;
}
__device__ inline float u2f_hi(unsigned int u) {
    union { unsigned int i; float f; } x; x.i = u & 0xFFFF0000u; return x.f;
}

// =============== two-phase binned scatter (r7 structure, launch-dieted) ===============
// hist40 also zeroes ovf_cnt (replaces the hipMemsetAsync dispatch);
// place40 also reduces SH -> cnt_s (replaces the sreduce dispatch).
__global__ __launch_bounds__(1024) void hist40_kernel(const int* __restrict__ src,
                                                      const int* __restrict__ dst,
                                                      unsigned int* __restrict__ H40,
                                                      unsigned int* __restrict__ SH,
                                                      int* __restrict__ ovf_cnt, int nE) {
    __shared__ unsigned int hb[BINS];
    __shared__ unsigned int hs[NW];   // 50 KB src byte counters
    if (blockIdx.x == 0 && threadIdx.x == 0) ovf_cnt[0] = 0;
    for (int i = threadIdx.x; i < NW; i += 1024) hs[i] = 0u;
    if (threadIdx.x < BINS) hb[threadIdx.x] = 0u;
    __syncthreads();
    int e0 = blockIdx.x * CH1;
    int e1 = min(e0 + CH1, nE);
    for (int e = e0 + (int)threadIdx.x; e < e1; e += 1024) {
        int s = src[e];
        int d = dst[e];
        atomicAdd(&hs[s >> 2], 1u << (8 * (s & 3)));   // per-chunk count <= out-degree < 256
        atomicAdd(&hb[d / PNODES], 1u);
    }
    __syncthreads();
    if (threadIdx.x < BINS) H40[blockIdx.x * BINS + threadIdx.x] = hb[threadIdx.x];
    unsigned int* SHb = SH + (size_t)blockIdx.x * NW;
    for (int i = threadIdx.x; i < NW; i += 1024) SHb[i] = hs[i];
}

__global__ void scan40_kernel(const unsigned int* __restrict__ H40,
                              unsigned int* __restrict__ OFF40,
                              unsigned int* __restrict__ binBase,
                              unsigned int* __restrict__ binTot) {
    __shared__ unsigned int part[B1 * BINS];   // 10 KB
    __shared__ unsigned int tot[BINS], base[BINS];
    int j = (int)threadIdx.x;
    if (j < BINS) {
        unsigned int run = 0;
        for (int b = 0; b < B1; b++) {
            part[b * BINS + j] = run;
            run += H40[b * BINS + j];
        }
        tot[j] = run;
    }
    __syncthreads();
    if (j == 0) {
        unsigned int run = 0;
        for (int q = 0; q < BINS; q++) { base[q] = run; run += tot[q]; }
    }
    __syncthreads();
    if (j < BINS) {
        binBase[j] = base[j];
        binTot[j] = tot[j];
        for (int b = 0; b < B1; b++) OFF40[b * BINS + j] = part[b * BINS + j] + base[j];
    }
}

__global__ __launch_bounds__(1024) void place40_kernel(const int* __restrict__ src,
                                                       const int* __restrict__ dst,
                                                       const unsigned int* __restrict__ OFF40,
                                                       unsigned int* __restrict__ binned,
                                                       const unsigned int* __restrict__ SH,
                                                       int* __restrict__ cnt_s, int nE) {
    __shared__ unsigned int cur[BINS];
    if (threadIdx.x < BINS) cur[threadIdx.x] = OFF40[blockIdx.x * BINS + threadIdx.x];
    __syncthreads();
    int e0 = blockIdx.x * CH1;
    int e1 = min(e0 + CH1, nE);
    for (int e = e0 + (int)threadIdx.x; e < e1; e += 1024) {
        int s = src[e];
        int d = dst[e];
        int bin = d / PNODES;
        unsigned int pos = atomicAdd(&cur[bin], 1u);
        binned[pos] = (unsigned int)(d - bin * PNODES) | ((unsigned int)s << 16);
    }
    // appended sreduce: cnt_s from the (complete, hist40-written) SH array
    int w = blockIdx.x * WPB + (int)threadIdx.x;
    if ((int)threadIdx.x < WPB && w < NW) {
        unsigned int run = 0;
#pragma unroll 8
        for (int b = 0; b < B1; b++) run += SH[(size_t)b * NW + w];  // SWAR
        int4 c;
        c.x = (int)(run & 0xFFu); c.y = (int)((run >> 8) & 0xFFu);
        c.z = (int)((run >> 16) & 0xFFu); c.w = (int)(run >> 24);
        ((int4*)cnt_s)[w] = c;
    }
}

__global__ __launch_bounds__(1024) void scatter2_kernel(
    const unsigned int* __restrict__ binned, const unsigned int* __restrict__ binBase,
    const unsigned int* __restrict__ binTot, unsigned short* __restrict__ bucket,
    int* __restrict__ cnt_d, int* __restrict__ ovf_cnt, int2* __restrict__ ovf) {
    __shared__ unsigned short bk[PNODES * CAP];  // 120 KB
    __shared__ unsigned int cur[PNODES];         // 5 KB
    const int j = blockIdx.x;
    const int nbeg = j * PNODES;
    for (int i = threadIdx.x; i < PNODES; i += 1024) cur[i] = 0u;
    __syncthreads();
    unsigned int b0 = binBase[j];
    unsigned int n = binTot[j];
    for (unsigned int i = threadIdx.x; i < n; i += 1024) {
        unsigned int v = binned[b0 + i];
        unsigned int dl = v & 0xFFFFu;
        unsigned int s = v >> 16;
        unsigned int q = atomicAdd(&cur[dl], 1u);
        if (q < CAP) {
            bk[dl * CAP + q] = (unsigned short)s;
        } else {
            int o = atomicAdd(ovf_cnt, 1);
            if (o < OVF_CAP) ovf[o] = make_int2(nbeg + (int)dl, (int)s);
        }
    }
    __syncthreads();
    uint4* gb = (uint4*)(bucket + (size_t)nbeg * CAP);
    const uint4* lb = (const uint4*)bk;
    const int n16 = PNODES * CAP * 2 / 16;   // 7500 uint4
    for (int i = threadIdx.x; i < n16; i += 1024) gb[i] = lb[i];
    for (int i = threadIdx.x; i < PNODES; i += 1024) cnt_d[nbeg + i] = (int)cur[i];
}

// ---------------- fused: rs arrays + xs = bf16(x * rs_out), ROW-MAJOR ----------------
__global__ void prescale_kernel(const float4* __restrict__ x, const int* __restrict__ cnt_s,
                                const int* __restrict__ cnt_d,
                                float* __restrict__ rs_out, float* __restrict__ rs_in,
                                ushort4* __restrict__ xs4, int nN) {
    int node = blockIdx.x * 8 + (threadIdx.x >> 5);
    int c = threadIdx.x & 31;
    if (node >= nN) return;
    float rs_o = 0.0f;
    if (c == 0) {
        rs_o = rsqrtf(fmaxf((float)cnt_s[node], 1.0f));
        rs_out[node] = rs_o;
        rs_in[node] = rsqrtf(fmaxf((float)cnt_d[node], 1.0f));
    }
    rs_o = __shfl(rs_o, threadIdx.x & 32);  // broadcast from node's lane 0 / 32
    float4 v = x[(size_t)node * 32 + c];
    ushort4 o;
    o.x = f2bf(v.x * rs_o);
    o.y = f2bf(v.y * rs_o);
    o.z = f2bf(v.z * rs_o);
    o.w = f2bf(v.w * rs_o);
    xs4[(size_t)node * 32 + c] = o;   // row-major: node row = 256 B
}

// ---------------- W hi/lo split into MFMA B-fragment layout ----------------
// Wf layout: [hi | lo], each 2048 frags of short8. frag index flat = (ks*8+c)*64+lane;
// element j: B[k = ks*32 + (lane>>4)*8 + j][n = c*16 + (lane&15)]  (B = W, K x N row-major).
__global__ void wsplit_kernel(const float* __restrict__ W1, bf16_t* __restrict__ Wf1,
                              const float* __restrict__ W2, bf16_t* __restrict__ Wf2) {
    const float* W = blockIdx.y ? W2 : W1;
    bf16_t* Wf = blockIdx.y ? Wf2 : Wf1;
    int flat = blockIdx.x * 256 + (int)threadIdx.x;   // 0..2047 (grid.x = 8)
    int lane = flat & 63;
    int c = (flat >> 6) & 7;
    int ks = flat >> 9;
    int n = c * 16 + (lane & 15);
    int kb = ks * 32 + (lane >> 4) * 8;
#pragma unroll
    for (int j = 0; j < 8; j++) {
        float w = W[(size_t)(kb + j) * D + n];
        bf16_t hi = f2bf(w);
        bf16_t lo = f2bf(w - bf2f(hi));
        Wf[(size_t)flat * 8 + j] = hi;
        Wf[(size_t)(2048 + flat) * 8 + j] = lo;
    }
}

// =============== fused gather + ovf-patch + MFMA gemm, 512 threads ===============
// r8 evidence: 43.7 us, Occupancy 24.7% (grid-limited: 782 blocks x 4 waves =
// 12 waves/CU cap), VALUBusy 21%, fabric 2 TB/s -> latency-bound gather.
// Fix: 8 waves/block (same 64-node tile, same LDS): phase 1 gathers 2 rows per
// thread (2x in-flight loads per CU); phase 2 splits each 16-node tile across
// a wave PAIR (each wave computes a 64-col half, acc[4]).
#define LDW 132
template <bool RELU_OUTSCALE, bool OUT_BF16>
__global__ __launch_bounds__(512) void fused_layer_kernel(
    const uint4* __restrict__ xsrc,          // bf16 row-major src features: 16 uint4/row
    const int* __restrict__ cnt_d,
    const unsigned short* __restrict__ bucket,
    const int* __restrict__ ovf_cnt, const int2* __restrict__ ovf,
    const float* __restrict__ rs_in, const float* __restrict__ rs_out,
    const bf16_t* __restrict__ Wf, const float* __restrict__ bias,
    void* __restrict__ outp, int nN) {
    __shared__ float sA[64 * LDW];   // 33.8 KB
    int tid = (int)threadIdx.x;
    int n0 = blockIdx.x * 64;
    int lane16 = tid & 15;
    int grp = tid >> 4;        // 0..31

    // ---- phase 1: gather 64 node rows into sA (2 rows/thread) ----
#define ACC8(v)                                              \
    a[0] += u2f_lo(v.x); a[1] += u2f_hi(v.x);                \
    a[2] += u2f_lo(v.y); a[3] += u2f_hi(v.y);                \
    a[4] += u2f_lo(v.z); a[5] += u2f_hi(v.z);                \
    a[6] += u2f_lo(v.w); a[7] += u2f_hi(v.w);
#pragma unroll
    for (int r = 0; r < 2; r++) {
        int ln = r * 32 + grp;     // local node 0..63
        int node = n0 + ln;
        float a[8];
#pragma unroll
        for (int k = 0; k < 8; k++) a[k] = 0.f;
        if (node < nN) {
            const unsigned short* bk = bucket + (size_t)node * CAP;
            int cnt = min(cnt_d[node], CAP);
            int e = 0;
            for (; e + 3 < cnt; e += 4) {
                int s0 = bk[e], s1 = bk[e + 1], s2 = bk[e + 2], s3 = bk[e + 3];
                uint4 v0 = xsrc[(size_t)s0 * 16 + lane16];
                uint4 v1 = xsrc[(size_t)s1 * 16 + lane16];
                uint4 v2 = xsrc[(size_t)s2 * 16 + lane16];
                uint4 v3 = xsrc[(size_t)s3 * 16 + lane16];
                ACC8(v0) ACC8(v1) ACC8(v2) ACC8(v3)
            }
            for (; e < cnt; e++) {
                int s0 = bk[e];
                uint4 v0 = xsrc[(size_t)s0 * 16 + lane16];
                ACC8(v0)
            }
        }
        float* row = sA + ln * LDW + lane16 * 8;
#pragma unroll
        for (int k = 0; k < 8; k++) row[k] = a[k];
    }
#undef ACC8

    // ---- overflow patch (uniform branch; no-op when list empty) ----
    int novf = min(*ovf_cnt, OVF_CAP);
    if (novf > 0) {
        __syncthreads();
        for (int i = tid; i < novf; i += 512) {
            int2 ds = ovf[i];
            int ln = ds.x - n0;
            if ((unsigned)ln < 64u) {
                const uint4* xr = xsrc + (size_t)ds.y * 16;
                for (int c = 0; c < 16; c++) {
                    uint4 v = xr[c];
                    float* q = sA + ln * LDW + c * 8;
                    atomicAdd(q + 0, u2f_lo(v.x)); atomicAdd(q + 1, u2f_hi(v.x));
                    atomicAdd(q + 2, u2f_lo(v.y)); atomicAdd(q + 3, u2f_hi(v.y));
                    atomicAdd(q + 4, u2f_lo(v.z)); atomicAdd(q + 5, u2f_hi(v.z));
                    atomicAdd(q + 6, u2f_lo(v.w)); atomicAdd(q + 7, u2f_hi(v.w));
                }
            }
        }
    }
    __syncthreads();

    // ---- phase 2: split-bf16 MFMA from LDS; wave pair per 16-node tile ----
    int lane = tid & 63;
    int wave = tid >> 6;       // 0..7
    int tile = wave >> 1;      // 0..3: node tile
    int half = wave & 1;       // 0..1: column half (64 cols)
    int ar = lane & 15;        // A row within tile
    int kg = lane >> 4;        // k-subchunk of 8
    const float* ap = sA + (tile * 16 + ar) * LDW + kg * 8;
    short8v ahi[4], alo[4];
#pragma unroll
    for (int ks = 0; ks < 4; ks++) {
#pragma unroll
        for (int j = 0; j < 8; j++) {
            float av = ap[ks * 32 + j];
            bf16_t h = f2bf(av);
            ahi[ks][j] = (short)h;
            alo[ks][j] = (short)f2bf(av - bf2f(h));
        }
    }

    f32x4 acc[4];
#pragma unroll
    for (int c = 0; c < 4; c++) acc[c] = (f32x4){0.f, 0.f, 0.f, 0.f};

    const short8v* Bh = (const short8v*)Wf;        // 2048 hi frags
    const short8v* Bl = Bh + 2048;                 // 2048 lo frags
#pragma unroll
    for (int ks = 0; ks < 4; ks++) {
#pragma unroll
        for (int c = 0; c < 4; c++) {
            int off = (ks * 8 + half * 4 + c) * 64 + lane;
            short8v wh = Bh[off];
            short8v wl = Bl[off];
            acc[c] = __builtin_amdgcn_mfma_f32_16x16x32_bf16(ahi[ks], wh, acc[c], 0, 0, 0);
            acc[c] = __builtin_amdgcn_mfma_f32_16x16x32_bf16(alo[ks], wh, acc[c], 0, 0, 0);
            acc[c] = __builtin_amdgcn_mfma_f32_16x16x32_bf16(ahi[ks], wl, acc[c], 0, 0, 0);
        }
    }

    // ---- epilogue: col = half*64 + c*16 + (lane&15), node = n0 + tile*16 + kg*4 + r ----
    int ocol = lane & 15;
#pragma unroll
    for (int r = 0; r < 4; r++) {
        int node = n0 + tile * 16 + kg * 4 + r;
        if (node >= nN) continue;
        float ri = rs_in[node];
        float ro = RELU_OUTSCALE ? rs_out[node] : 1.0f;
#pragma unroll
        for (int c = 0; c < 4; c++) {
            int col = half * 64 + c * 16 + ocol;
            float v = acc[c][r] * ri + bias[col];
            if (RELU_OUTSCALE) v = fmaxf(v, 0.0f) * ro;
            if (OUT_BF16) {
                ((bf16_t*)outp)[(size_t)node * D + col] = f2bf(v);
            } else {
                ((float*)outp)[(size_t)node * D + col] = v;
            }
        }
    }
}
#undef LDW

static inline size_t align16(size_t x) { return (x + 15) & ~(size_t)15; }

extern "C" void kernel_launch(void* const* d_in, const int* in_sizes, int n_in,
                              void* d_out, int out_size, void* d_ws, size_t ws_size,
                              hipStream_t stream) {
    const float* x   = (const float*)d_in[0];
    const int*   src = (const int*)d_in[1];
    const int*   dst = (const int*)d_in[2];
    const float* W1  = (const float*)d_in[3];
    const float* b1  = (const float*)d_in[4];
    const float* W2  = (const float*)d_in[5];
    const float* b2  = (const float*)d_in[6];
    float* out = (float*)d_out;

    char* p = (char*)d_ws;
    int*            cnt_s   = (int*)p;            p += align16(N_NODES * sizeof(int));
    int*            cnt_d   = (int*)p;            p += align16(N_NODES * sizeof(int));
    int*            ovf_cnt = (int*)p;            p += align16(16 * sizeof(int));
    int2*           ovf     = (int2*)p;           p += align16((size_t)OVF_CAP * sizeof(int2));
    unsigned short* bucket  = (unsigned short*)p; p += align16((size_t)N_NODES * CAP * sizeof(unsigned short));
    float*          rs_out  = (float*)p;          p += align16(N_NODES * sizeof(float));
    float*          rs_in   = (float*)p;          p += align16(N_NODES * sizeof(float));
    bf16_t*         Wf1     = (bf16_t*)p;         p += align16((size_t)2 * 2048 * 8 * sizeof(bf16_t));
    bf16_t*         Wf2     = (bf16_t*)p;         p += align16((size_t)2 * 2048 * 8 * sizeof(bf16_t));
    unsigned int*   H40     = (unsigned int*)p;   p += align16((size_t)B1 * BINS * sizeof(unsigned int));
    unsigned int*   OFF40   = (unsigned int*)p;   p += align16((size_t)B1 * BINS * sizeof(unsigned int));
    unsigned int*   binBase = (unsigned int*)p;   p += align16(BINS * sizeof(unsigned int));
    unsigned int*   binTot  = (unsigned int*)p;   p += align16(BINS * sizeof(unsigned int));
    unsigned int*   binned  = (unsigned int*)p;   p += align16((size_t)N_EDGES * sizeof(unsigned int));
    unsigned int*   SH      = (unsigned int*)p;   p += align16((size_t)B1 * NW * sizeof(unsigned int));
    bf16_t*         xs      = (bf16_t*)p;         p += align16((size_t)N_NODES * D * sizeof(bf16_t));
    bf16_t*         hs      = (bf16_t*)p;         // separate 12.8 MB buffer

    // weight hi/lo split into MFMA fragment layout (both layers, one tiny launch)
    wsplit_kernel<<<dim3(8, 2), 256, 0, stream>>>(W1, Wf1, W2, Wf2);

    // two-phase binned scatter (hist40 zeroes ovf_cnt; place40 folds sreduce)
    hist40_kernel<<<B1, 1024, 0, stream>>>(src, dst, H40, SH, ovf_cnt, N_EDGES);
    scan40_kernel<<<1, 64, 0, stream>>>(H40, OFF40, binBase, binTot);
    place40_kernel<<<B1, 1024, 0, stream>>>(src, dst, OFF40, binned, SH, cnt_s, N_EDGES);
    scatter2_kernel<<<BINS, 1024, 0, stream>>>(binned, binBase, binTot, bucket,
                                               cnt_d, ovf_cnt, ovf);

    // rs arrays + xs = bf16(x * rs_out), row-major
    prescale_kernel<<<(N_NODES + 7) / 8, 256, 0, stream>>>((const float4*)x, cnt_s, cnt_d,
                                                           rs_out, rs_in, (ushort4*)xs, N_NODES);

    int fgrid = (N_NODES + 63) / 64;   // 64 nodes per fused block

    // layer 1: hs = bf16( relu(rs_in * (gather(xs) @ W1) + b1) * rs_out )
    fused_layer_kernel<true, true><<<fgrid, 512, 0, stream>>>(
        (const uint4*)xs, cnt_d, bucket, ovf_cnt, ovf, rs_in, rs_out, Wf1, b1, hs, N_NODES);

    // layer 2: out = rs_in * (gather(hs) @ W2) + b2   (fp32 row-major)
    fused_layer_kernel<false, false><<<fgrid, 512, 0, stream>>>(
        (const uint4*)hs, cnt_d, bucket, ovf_cnt, ovf, rs_in, rs_out, Wf2, b2, out, N_NODES);
}